// Round 1
// baseline (2237.697 us; speedup 1.0000x reference)
//
#include <hip/hip_runtime.h>
#include <math.h>

#define NB 512
#define NI 8192
#define NLOG2 0.69314718055994530942f  // rounds to 0x3F317218, same as jnp.log(2.0) in f32

__device__ __forceinline__ float log1mexp_f(float x) {
    // log(1 - exp(x)) for x <= 0, matching reference branch structure
    return (x > -NLOG2) ? logf(-expm1f(x)) : log1pf(-expf(x));
}

// ---------------- Kernel 1: parallel prep: lp, lq per item ----------------
__global__ __launch_bounds__(256) void prep_kernel(const float* __restrict__ logits,
                                                   float* __restrict__ Alp,   // -> ws (later x1)
                                                   float* __restrict__ Blq) { // -> d_out (later S1, then output)
    int idx = blockIdx.x * blockDim.x + threadIdx.x;  // float4 group index
    float4 x4 = ((const float4*)logits)[idx];
    float4 lp4, lq4;
    const float* xs = &x4.x;
    float* lps = &lp4.x;
    float* lqs = &lq4.x;
#pragma unroll
    for (int j = 0; j < 4; ++j) {
        float x = xs[j];
        // log_sigmoid(x) = -softplus(-x) = -(max(-x,0) + log1p(exp(-|x|)))
        float lp = -(fmaxf(-x, 0.0f) + log1pf(expf(-fabsf(x))));
        lp = fminf(lp, -1e-7f);
        lps[j] = lp;
        lqs[j] = log1mexp_f(lp);
    }
    ((float4*)Alp)[idx] = lp4;
    ((float4*)Blq)[idx] = lq4;
}

// ---------------- Kernel 2: sequential per-row scan (512 lanes = 8 waves) ----------------
// In: A = lp, B = lq. Out (in place): A = x1 (= S0[i-1]+lp_i), B = S1[i].
// Exact fp32 sequential fold, same op order as the jax scan.
#define CH 32
__global__ __launch_bounds__(64, 1) void scan_kernel(float* __restrict__ A,
                                                     float* __restrict__ B) {
    int row = blockIdx.x * blockDim.x + threadIdx.x;
    float* Ar = A + (size_t)row * NI;
    float* Br = B + (size_t)row * NI;

    float S0 = 0.0f;
    float S1 = -INFINITY;

    float lpA[CH], lqA[CH], lpB[CH], lqB[CH];
    float x1A[CH], s1A[CH], x1B[CH], s1B[CH];

    // preload chunk 0
#pragma unroll
    for (int j = 0; j < CH / 4; ++j) {
        *(float4*)&lpA[4 * j] = *(const float4*)&Ar[4 * j];
        *(float4*)&lqA[4 * j] = *(const float4*)&Br[4 * j];
    }

    const int NCHUNK = NI / CH;  // 256 (even)
    for (int c = 0; c < NCHUNK; c += 2) {
        const int base0 = c * CH, base1 = (c + 1) * CH, base2 = (c + 2) * CH;

        // prefetch chunk c+1 into B buffers (always valid: c+1 <= NCHUNK-1)
#pragma unroll
        for (int j = 0; j < CH / 4; ++j) {
            *(float4*)&lpB[4 * j] = *(const float4*)&Ar[base1 + 4 * j];
            *(float4*)&lqB[4 * j] = *(const float4*)&Br[base1 + 4 * j];
        }

        // compute chunk c
#pragma unroll
        for (int j = 0; j < CH; ++j) {
            float lp = lpA[j], lq = lqA[j];
            float x1 = S0 + lp;
            float x2 = S1 + lq;
            float d = x1 - x2;                       // never NaN: x1 always finite
            float t = log1pf(expf(-fabsf(d)));       // softplus(-|d|) for |d|>=0
            float m = fmaxf(x1, x2);
            S1 = m + t;
            S0 = S0 + lq;                            // exact col-1 update
            x1A[j] = x1;
            s1A[j] = S1;
        }
        // store chunk c (in place; all pending loads are at higher addresses)
#pragma unroll
        for (int j = 0; j < CH / 4; ++j) {
            *(float4*)&Ar[base0 + 4 * j] = *(float4*)&x1A[4 * j];
            *(float4*)&Br[base0 + 4 * j] = *(float4*)&s1A[4 * j];
        }

        // prefetch chunk c+2 into A buffers
        if (c + 2 < NCHUNK) {
#pragma unroll
            for (int j = 0; j < CH / 4; ++j) {
                *(float4*)&lpA[4 * j] = *(const float4*)&Ar[base2 + 4 * j];
                *(float4*)&lqA[4 * j] = *(const float4*)&Br[base2 + 4 * j];
            }
        }

        // compute chunk c+1
#pragma unroll
        for (int j = 0; j < CH; ++j) {
            float lp = lpB[j], lq = lqB[j];
            float x1 = S0 + lp;
            float x2 = S1 + lq;
            float d = x1 - x2;
            float t = log1pf(expf(-fabsf(d)));
            float m = fmaxf(x1, x2);
            S1 = m + t;
            S0 = S0 + lq;
            x1B[j] = x1;
            s1B[j] = S1;
        }
#pragma unroll
        for (int j = 0; j < CH / 4; ++j) {
            *(float4*)&Ar[base1 + 4 * j] = *(float4*)&x1B[4 * j];
            *(float4*)&Br[base1 + 4 * j] = *(float4*)&s1B[4 * j];
        }
    }
}

// ---------------- Kernel 3: parallel decide + argmax + output write ----------------
// One block per row. Reads x1 (ws), S1 (d_out), noise; writes 0/1 over d_out.
__global__ __launch_bounds__(256) void decide_kernel(const float* __restrict__ A,  // x1
                                                     const float* __restrict__ S,  // S1 (aliases out)
                                                     const float* __restrict__ noise,
                                                     float* __restrict__ out) {
    int row = blockIdx.x;
    const float4* x1r = (const float4*)(A + (size_t)row * NI);
    const float4* s1r = (const float4*)(S + (size_t)row * NI);
    const float4* ur = (const float4*)(noise + (size_t)row * NI);
    float4* outr = (float4*)(out + (size_t)row * NI);
    int tid = threadIdx.x;

    int best = -1;
#pragma unroll
    for (int k = 0; k < NI / 4 / 256; ++k) {  // 8
        int g = tid + k * 256;
        float4 x1 = x1r[g];
        float4 s1 = s1r[g];
        float4 u = ur[g];
#pragma unroll
        for (int j = 0; j < 4; ++j) {
            float p = fminf((&x1.x)[j] - (&s1.x)[j], 0.0f);
            float q = log1mexp_f(p);            // p==0 -> log(-0.0) = -inf -> prob 1
            float z = p - q;
            float prob = 1.0f / (1.0f + expf(-z));
            if ((&u.x)[j] < prob) {
                int i = 4 * g + j;
                best = (i > best) ? i : best;
            }
        }
    }

    // block max-reduce (4 waves)
#pragma unroll
    for (int off = 32; off > 0; off >>= 1) {
        int o = __shfl_down(best, off);
        best = (o > best) ? o : best;
    }
    __shared__ int lds[4];
    __shared__ int sel_s;
    int wid = tid >> 6;
    if ((tid & 63) == 0) lds[wid] = best;
    __syncthreads();
    if (tid == 0) {
        int s01 = (lds[0] > lds[1]) ? lds[0] : lds[1];
        int s23 = (lds[2] > lds[3]) ? lds[2] : lds[3];
        sel_s = (s01 > s23) ? s01 : s23;
    }
    __syncthreads();
    int sel = sel_s;

#pragma unroll
    for (int k = 0; k < NI / 4 / 256; ++k) {
        int g = tid + k * 256;
        int i0 = 4 * g;
        float4 v;
        v.x = (i0 == sel) ? 1.0f : 0.0f;
        v.y = (i0 + 1 == sel) ? 1.0f : 0.0f;
        v.z = (i0 + 2 == sel) ? 1.0f : 0.0f;
        v.w = (i0 + 3 == sel) ? 1.0f : 0.0f;
        outr[g] = v;
    }
}

extern "C" void kernel_launch(void* const* d_in, const int* in_sizes, int n_in,
                              void* d_out, int out_size, void* d_ws, size_t ws_size,
                              hipStream_t stream) {
    (void)in_sizes; (void)n_in; (void)out_size; (void)ws_size;
    const float* logits = (const float*)d_in[0];
    const float* noise = (const float*)d_in[1];
    float* out = (float*)d_out;       // lq -> S1 -> final 0/1 output (16 MB)
    float* A = (float*)d_ws;          // lp -> x1 (16 MB of ws)

    int total4 = NB * NI / 4;                                  // 1,048,576 float4 groups
    prep_kernel<<<total4 / 256, 256, 0, stream>>>(logits, A, out);
    scan_kernel<<<8, 64, 0, stream>>>(A, out);
    decide_kernel<<<NB, 256, 0, stream>>>(A, out, noise, out);
}

// Round 2
// 484.284 us; speedup vs baseline: 4.6206x; 4.6206x over previous
//
#include <hip/hip_runtime.h>
#include <math.h>

#define NB 512
#define NI 8192
#define NLOG2 0.69314718055994530942f

__device__ __forceinline__ float log1mexp_f(float x) {
    // log(1 - exp(x)) for x <= 0, matching reference branch structure (precise ocml)
    return (x > -NLOG2) ? logf(-expm1f(x)) : log1pf(-expf(x));
}

// ---------------- Kernel 1: parallel prep: lp, lq per item (precise, unchanged) -------
__global__ __launch_bounds__(256) void prep_kernel(const float* __restrict__ logits,
                                                   float* __restrict__ Alp,   // -> ws (later x1)
                                                   float* __restrict__ Blq) { // -> d_out (later S1, then output)
    int idx = blockIdx.x * blockDim.x + threadIdx.x;  // float4 group index
    float4 x4 = ((const float4*)logits)[idx];
    float4 lp4, lq4;
    const float* xs = &x4.x;
    float* lps = &lp4.x;
    float* lqs = &lq4.x;
#pragma unroll
    for (int j = 0; j < 4; ++j) {
        float x = xs[j];
        float lp = -(fmaxf(-x, 0.0f) + log1pf(expf(-fabsf(x))));
        lp = fminf(lp, -1e-7f);
        lps[j] = lp;
        lqs[j] = log1mexp_f(lp);
    }
    ((float4*)Alp)[idx] = lp4;
    ((float4*)Blq)[idx] = lq4;
}

// ---------------- Kernel 2: sequential per-row scan (512 lanes = 8 waves) ----------------
// In: A = lp, B = lq. Out (in place): A = x1 (= S0[i-1]+lp_i), B = S1[i].
// Large-magnitude fp32 adds kept in the reference's exact order; softplus internals
// use HW v_exp_f32/v_log_f32 (dependent chain: 7 ops vs ~60 for ocml).
#define CH 32
__device__ __forceinline__ void scan_step(float lp, float lq, float& S0, float& S1,
                                          float& x1o, float& s1o) {
    const float L2E = 1.44269504088896340736f;   // log2(e)
    const float LN2 = 0.69314718055994530942f;   // ln(2)
    float x1 = S0 + lp;
    float x2 = S1 + lq;
    float d  = x1 - x2;                          // Sterbenz-exact region; never NaN (x1 finite)
    float m  = fmaxf(x1, x2);
    float z  = fabsf(d) * -L2E;                  // single VOP3 mul w/ -abs modifier
    float e  = __builtin_amdgcn_exp2f(z);        // v_exp_f32; exp2(-inf)=0 handles S1=-inf start
    float a  = 1.0f + e;
    float l  = __builtin_amdgcn_logf(a);         // v_log_f32 = log2
    S1 = fmaf(l, LN2, m);                        // m + softplus(-|d|), single rounding
    S0 = S0 + lq;
    x1o = x1;
    s1o = S1;
}

__global__ __launch_bounds__(64, 1) void scan_kernel(float* __restrict__ A,
                                                     float* __restrict__ B) {
    int row = blockIdx.x * blockDim.x + threadIdx.x;
    float* Ar = A + (size_t)row * NI;
    float* Br = B + (size_t)row * NI;

    float S0 = 0.0f;
    float S1 = -INFINITY;

    float lpA[CH], lqA[CH], lpB[CH], lqB[CH];
    float x1A[CH], s1A[CH], x1B[CH], s1B[CH];

    // preload chunk 0
#pragma unroll
    for (int j = 0; j < CH / 4; ++j) {
        *(float4*)&lpA[4 * j] = *(const float4*)&Ar[4 * j];
        *(float4*)&lqA[4 * j] = *(const float4*)&Br[4 * j];
    }

    const int NCHUNK = NI / CH;  // 256 (even)
    for (int c = 0; c < NCHUNK; c += 2) {
        const int base0 = c * CH, base1 = (c + 1) * CH, base2 = (c + 2) * CH;

        // prefetch chunk c+1 into B buffers
#pragma unroll
        for (int j = 0; j < CH / 4; ++j) {
            *(float4*)&lpB[4 * j] = *(const float4*)&Ar[base1 + 4 * j];
            *(float4*)&lqB[4 * j] = *(const float4*)&Br[base1 + 4 * j];
        }

        // compute chunk c
#pragma unroll
        for (int j = 0; j < CH; ++j)
            scan_step(lpA[j], lqA[j], S0, S1, x1A[j], s1A[j]);
#pragma unroll
        for (int j = 0; j < CH / 4; ++j) {
            *(float4*)&Ar[base0 + 4 * j] = *(float4*)&x1A[4 * j];
            *(float4*)&Br[base0 + 4 * j] = *(float4*)&s1A[4 * j];
        }

        // prefetch chunk c+2 into A buffers
        if (c + 2 < NCHUNK) {
#pragma unroll
            for (int j = 0; j < CH / 4; ++j) {
                *(float4*)&lpA[4 * j] = *(const float4*)&Ar[base2 + 4 * j];
                *(float4*)&lqA[4 * j] = *(const float4*)&Br[base2 + 4 * j];
            }
        }

        // compute chunk c+1
#pragma unroll
        for (int j = 0; j < CH; ++j)
            scan_step(lpB[j], lqB[j], S0, S1, x1B[j], s1B[j]);
#pragma unroll
        for (int j = 0; j < CH / 4; ++j) {
            *(float4*)&Ar[base1 + 4 * j] = *(float4*)&x1B[4 * j];
            *(float4*)&Br[base1 + 4 * j] = *(float4*)&s1B[4 * j];
        }
    }
}

// ---------------- Kernel 3: parallel decide + argmax + output write (precise, unchanged) --
__global__ __launch_bounds__(256) void decide_kernel(const float* __restrict__ A,  // x1
                                                     const float* __restrict__ S,  // S1 (aliases out)
                                                     const float* __restrict__ noise,
                                                     float* __restrict__ out) {
    int row = blockIdx.x;
    const float4* x1r = (const float4*)(A + (size_t)row * NI);
    const float4* s1r = (const float4*)(S + (size_t)row * NI);
    const float4* ur = (const float4*)(noise + (size_t)row * NI);
    float4* outr = (float4*)(out + (size_t)row * NI);
    int tid = threadIdx.x;

    int best = -1;
#pragma unroll
    for (int k = 0; k < NI / 4 / 256; ++k) {  // 8
        int g = tid + k * 256;
        float4 x1 = x1r[g];
        float4 s1 = s1r[g];
        float4 u = ur[g];
#pragma unroll
        for (int j = 0; j < 4; ++j) {
            float p = fminf((&x1.x)[j] - (&s1.x)[j], 0.0f);
            float q = log1mexp_f(p);            // p==0 -> -inf -> prob 1
            float z = p - q;
            float prob = 1.0f / (1.0f + expf(-z));
            if ((&u.x)[j] < prob) {
                int i = 4 * g + j;
                best = (i > best) ? i : best;
            }
        }
    }

#pragma unroll
    for (int off = 32; off > 0; off >>= 1) {
        int o = __shfl_down(best, off);
        best = (o > best) ? o : best;
    }
    __shared__ int lds[4];
    __shared__ int sel_s;
    int wid = tid >> 6;
    if ((tid & 63) == 0) lds[wid] = best;
    __syncthreads();
    if (tid == 0) {
        int s01 = (lds[0] > lds[1]) ? lds[0] : lds[1];
        int s23 = (lds[2] > lds[3]) ? lds[2] : lds[3];
        sel_s = (s01 > s23) ? s01 : s23;
    }
    __syncthreads();
    int sel = sel_s;

#pragma unroll
    for (int k = 0; k < NI / 4 / 256; ++k) {
        int g = tid + k * 256;
        int i0 = 4 * g;
        float4 v;
        v.x = (i0 == sel) ? 1.0f : 0.0f;
        v.y = (i0 + 1 == sel) ? 1.0f : 0.0f;
        v.z = (i0 + 2 == sel) ? 1.0f : 0.0f;
        v.w = (i0 + 3 == sel) ? 1.0f : 0.0f;
        outr[g] = v;
    }
}

extern "C" void kernel_launch(void* const* d_in, const int* in_sizes, int n_in,
                              void* d_out, int out_size, void* d_ws, size_t ws_size,
                              hipStream_t stream) {
    (void)in_sizes; (void)n_in; (void)out_size; (void)ws_size;
    const float* logits = (const float*)d_in[0];
    const float* noise = (const float*)d_in[1];
    float* out = (float*)d_out;       // lq -> S1 -> final 0/1 output (16 MB)
    float* A = (float*)d_ws;          // lp -> x1 (16 MB of ws)

    int total4 = NB * NI / 4;
    prep_kernel<<<total4 / 256, 256, 0, stream>>>(logits, A, out);
    scan_kernel<<<8, 64, 0, stream>>>(A, out);
    decide_kernel<<<NB, 256, 0, stream>>>(A, out, noise, out);
}